// Round 1
// baseline (76.569 us; speedup 1.0000x reference)
//
#include <hip/hip_runtime.h>
#include <cmath>

// SE block: windowed mean-pool -> softsign(mW1+b1) -> sigmoid(softsign(hW2+b2)) -> gate x.
// B=32, M=2048, D=512, H=64, WIN=16 (M % WIN == 0 so reference's edge-pad is a no-op).
// One 256-thread block per (b, window). Window x kept in registers (8 x float4/thread).

constexpr int WIN = 16;
constexpr int D   = 512;
constexpr int H   = 64;
constexpr int TPB = 256;

__global__ __launch_bounds__(TPB) void se_block_kernel(
    const float* __restrict__ x,
    const float* __restrict__ W1,
    const float* __restrict__ b1,
    const float* __restrict__ W2,
    const float* __restrict__ b2,
    float* __restrict__ y)
{
    const int tid = threadIdx.x;
    const size_t base = (size_t)blockIdx.x * (size_t)(WIN * D); // window is contiguous WIN*D floats
    const float4* __restrict__ xw = reinterpret_cast<const float4*>(x + base);
    float4*       __restrict__ yw = reinterpret_cast<float4*>(y + base);

    __shared__ float4 s_ps[TPB];      // partial sums for mean        (4 KB)
    __shared__ float  s_m[D];         // window mean                  (2 KB)
    __shared__ float  s_hp[4][H];     // partial dot products for h   (1 KB)
    __shared__ float  s_h[H];         // hidden activations           (256 B)
    __shared__ float2 s_g[D / 2];     // gate                         (2 KB)

    // ---- Load window into registers: thread owns column-group (tid&127), rows (tid<128 ? even : odd)
    float4 r[8];
#pragma unroll
    for (int i = 0; i < 8; ++i) r[i] = xw[i * TPB + tid];

    // ---- Mean over WIN (time) axis
    float4 ps = r[0];
#pragma unroll
    for (int i = 1; i < 8; ++i) {
        ps.x += r[i].x; ps.y += r[i].y; ps.z += r[i].z; ps.w += r[i].w;
    }
    s_ps[tid] = ps;
    __syncthreads();

    if (tid < 128) {
        float4 a = s_ps[tid];
        float4 b = s_ps[tid + 128];
        s_m[tid * 4 + 0] = (a.x + b.x) * (1.0f / 16.0f);
        s_m[tid * 4 + 1] = (a.y + b.y) * (1.0f / 16.0f);
        s_m[tid * 4 + 2] = (a.z + b.z) * (1.0f / 16.0f);
        s_m[tid * 4 + 3] = (a.w + b.w) * (1.0f / 16.0f);
    }
    __syncthreads();

    // ---- h[j] = softsign(sum_k m[k]*W1[k][j] + b1[j]); 4 partial-sum groups of 128 k each
    {
        const int j    = tid & (H - 1);
        const int part = tid >> 6;          // one wave == one part -> s_m reads are broadcast
        const int k0   = part * (D / 4);
        float acc = 0.0f;
#pragma unroll 4
        for (int k = 0; k < D / 4; ++k) {
            acc = fmaf(s_m[k0 + k], W1[(size_t)(k0 + k) * H + j], acc);
        }
        s_hp[part][j] = acc;
    }
    __syncthreads();
    if (tid < H) {
        float s = s_hp[0][tid] + s_hp[1][tid] + s_hp[2][tid] + s_hp[3][tid] + b1[tid];
        s_h[tid] = s / (1.0f + fabsf(s));
    }
    __syncthreads();

    // ---- g[d] = sigmoid(softsign(sum_j h[j]*W2[j][d] + b2[d])); thread handles d = 2*tid, 2*tid+1
    {
        const float2* __restrict__ W2f2 = reinterpret_cast<const float2*>(W2);
        float ax = 0.0f, ay = 0.0f;
#pragma unroll 8
        for (int jj = 0; jj < H; ++jj) {
            const float  hv = s_h[jj];                       // broadcast (same addr all lanes)
            const float2 w  = W2f2[(size_t)jj * (D / 2) + tid]; // coalesced 8B/lane
            ax = fmaf(hv, w.x, ax);
            ay = fmaf(hv, w.y, ay);
        }
        const float2 bb = reinterpret_cast<const float2*>(b2)[tid];
        float sx = ax + bb.x;
        float sy = ay + bb.y;
        sx = sx / (1.0f + fabsf(sx));       // softsign, result in (-1,1)
        sy = sy / (1.0f + fabsf(sy));
        const float gx = 1.0f / (1.0f + __expf(-sx));  // sigmoid; arg bounded so __expf is safe
        const float gy = 1.0f / (1.0f + __expf(-sy));
        s_g[tid] = make_float2(gx, gy);
    }
    __syncthreads();

    // ---- Apply gate and store. Thread's column-group is constant across its 8 rows:
    //      (i*256 + tid) mod 128 == tid mod 128  -> one LDS float4 read, reused 8x.
    const float4* __restrict__ gp = reinterpret_cast<const float4*>(s_g);
    const float4 g = gp[tid & 127];
#pragma unroll
    for (int i = 0; i < 8; ++i) {
        float4 o;
        o.x = r[i].x * g.x;
        o.y = r[i].y * g.y;
        o.z = r[i].z * g.z;
        o.w = r[i].w * g.w;
        yw[i * TPB + tid] = o;
    }
}

extern "C" void kernel_launch(void* const* d_in, const int* in_sizes, int n_in,
                              void* d_out, int out_size, void* d_ws, size_t ws_size,
                              hipStream_t stream) {
    const float* x  = (const float*)d_in[0];
    const float* W1 = (const float*)d_in[1];
    const float* b1 = (const float*)d_in[2];
    const float* W2 = (const float*)d_in[3];
    const float* b2 = (const float*)d_in[4];
    float* y = (float*)d_out;

    const int n_windows = in_sizes[0] / (WIN * D); // B * (M/WIN) = 4096
    se_block_kernel<<<dim3(n_windows), dim3(TPB), 0, stream>>>(x, W1, b1, W2, b2, y);
}

// Round 2
// 59.842 us; speedup vs baseline: 1.2795x; 1.2795x over previous
//
#include <hip/hip_runtime.h>
#include <cmath>

// SE block: windowed mean-pool -> softsign(mW1+b1) -> sigmoid(softsign(hW2+b2)) -> gate x.
// B=32, M=2048, D=512, H=64, WIN=16 (M % WIN == 0, so reference edge-pad is a no-op).
// One 256-thread block per window; window x held in registers (8 x float4/thread).
// R1: float4 weight loads + split-K partials (was 128 scalar L2 loads/thread -> latency-bound).

constexpr int WIN = 16;
constexpr int D   = 512;
constexpr int H   = 64;
constexpr int TPB = 256;

__global__ __launch_bounds__(TPB) void se_block_kernel(
    const float* __restrict__ x,
    const float* __restrict__ W1,
    const float* __restrict__ b1,
    const float* __restrict__ W2,
    const float* __restrict__ b2,
    float* __restrict__ y)
{
    const int tid = threadIdx.x;
    const size_t base = (size_t)blockIdx.x * (size_t)(WIN * D); // window: contiguous WIN*D floats
    const float4* __restrict__ xw = reinterpret_cast<const float4*>(x + base);
    float4*       __restrict__ yw = reinterpret_cast<float4*>(y + base);

    const float4* __restrict__ W1f4 = reinterpret_cast<const float4*>(W1); // [512][16] of float4
    const float4* __restrict__ W2f4 = reinterpret_cast<const float4*>(W2); // [64][128] of float4

    __shared__ float4 s_ps[TPB];        // per-thread partial sums (col-group, row-parity)  4 KB
    __shared__ float  s_hp[16][H];      // matmul1 partials (16-way k-split)                 4 KB
    __shared__ float  s_h[H];           // hidden activations                                256 B
    __shared__ float  s_gp[2][D];       // matmul2 partials (2-way j-split)                  4 KB
    __shared__ float  s_g[D];           // gate                                              2 KB

    // ---- Load window into registers.
    // element e = i*256+tid (float4 units): col c = tid&127, row = 2*i + (tid>>7).
    float4 r[8];
#pragma unroll
    for (int i = 0; i < 8; ++i) r[i] = xw[i * TPB + tid];

    // ---- Per-thread partial sum over its 8 rows (half of the 16-row window for its col).
    float4 ps = r[0];
#pragma unroll
    for (int i = 1; i < 8; ++i) {
        ps.x += r[i].x; ps.y += r[i].y; ps.z += r[i].z; ps.w += r[i].w;
    }
    s_ps[tid] = ps;
    __syncthreads();

    // ---- matmul1: h_pre[j] = sum_k m[k]*W1[k][j].  16-way k-split.
    // thread -> (p = tid>>4 in [0,16), j4 = tid&15).  k in [p*32, p*32+32).
    // m folded in: m4[c4] = (s_ps[c4] + s_ps[c4+128]) * (1/16), scale deferred to the write.
    {
        const int p  = tid >> 4;
        const int j4 = tid & 15;
        float4 acc = make_float4(0.f, 0.f, 0.f, 0.f);
#pragma unroll 2
        for (int kk4 = 0; kk4 < 8; ++kk4) {
            const int c4 = p * 8 + kk4;              // float4-group index of m
            const float4 a = s_ps[c4];
            const float4 b = s_ps[c4 + 128];
            const float mv0 = a.x + b.x, mv1 = a.y + b.y, mv2 = a.z + b.z, mv3 = a.w + b.w;
            const int k = c4 * 4;
            const float4 w0 = W1f4[(size_t)(k + 0) * 16 + j4];
            const float4 w1 = W1f4[(size_t)(k + 1) * 16 + j4];
            const float4 w2 = W1f4[(size_t)(k + 2) * 16 + j4];
            const float4 w3 = W1f4[(size_t)(k + 3) * 16 + j4];
            acc.x = fmaf(mv0, w0.x, acc.x); acc.y = fmaf(mv0, w0.y, acc.y);
            acc.z = fmaf(mv0, w0.z, acc.z); acc.w = fmaf(mv0, w0.w, acc.w);
            acc.x = fmaf(mv1, w1.x, acc.x); acc.y = fmaf(mv1, w1.y, acc.y);
            acc.z = fmaf(mv1, w1.z, acc.z); acc.w = fmaf(mv1, w1.w, acc.w);
            acc.x = fmaf(mv2, w2.x, acc.x); acc.y = fmaf(mv2, w2.y, acc.y);
            acc.z = fmaf(mv2, w2.z, acc.z); acc.w = fmaf(mv2, w2.w, acc.w);
            acc.x = fmaf(mv3, w3.x, acc.x); acc.y = fmaf(mv3, w3.y, acc.y);
            acc.z = fmaf(mv3, w3.z, acc.z); acc.w = fmaf(mv3, w3.w, acc.w);
        }
        const float sc = 1.0f / 16.0f;               // the deferred mean scale
        s_hp[p][j4 * 4 + 0] = acc.x * sc;
        s_hp[p][j4 * 4 + 1] = acc.y * sc;
        s_hp[p][j4 * 4 + 2] = acc.z * sc;
        s_hp[p][j4 * 4 + 3] = acc.w * sc;
    }
    __syncthreads();

    // ---- finalize h: reduce 16 partials, add b1, softsign.
    if (tid < H) {
        float s = b1[tid];
#pragma unroll
        for (int p = 0; p < 16; ++p) s += s_hp[p][tid];
        s_h[tid] = s / (1.0f + fabsf(s));
    }
    __syncthreads();

    // ---- matmul2: g_pre[d] = sum_j h[j]*W2[j][d].  2-way j-split.
    // thread -> (q = tid>>7 in {0,1}, d4 = tid&127).  j in [q*32, q*32+32).
    {
        const int q  = tid >> 7;
        const int d4 = tid & 127;
        const float4* __restrict__ s_h4 = reinterpret_cast<const float4*>(s_h);
        float4 acc = make_float4(0.f, 0.f, 0.f, 0.f);
#pragma unroll 2
        for (int jj4 = 0; jj4 < 8; ++jj4) {
            const float4 hv = s_h4[q * 8 + jj4];
            const int j = (q * 8 + jj4) * 4;
            const float4 w0 = W2f4[(size_t)(j + 0) * 128 + d4];
            const float4 w1 = W2f4[(size_t)(j + 1) * 128 + d4];
            const float4 w2 = W2f4[(size_t)(j + 2) * 128 + d4];
            const float4 w3 = W2f4[(size_t)(j + 3) * 128 + d4];
            acc.x = fmaf(hv.x, w0.x, acc.x); acc.y = fmaf(hv.x, w0.y, acc.y);
            acc.z = fmaf(hv.x, w0.z, acc.z); acc.w = fmaf(hv.x, w0.w, acc.w);
            acc.x = fmaf(hv.y, w1.x, acc.x); acc.y = fmaf(hv.y, w1.y, acc.y);
            acc.z = fmaf(hv.y, w1.z, acc.z); acc.w = fmaf(hv.y, w1.w, acc.w);
            acc.x = fmaf(hv.z, w2.x, acc.x); acc.y = fmaf(hv.z, w2.y, acc.y);
            acc.z = fmaf(hv.z, w2.z, acc.z); acc.w = fmaf(hv.z, w2.w, acc.w);
            acc.x = fmaf(hv.w, w3.x, acc.x); acc.y = fmaf(hv.w, w3.y, acc.y);
            acc.z = fmaf(hv.w, w3.z, acc.z); acc.w = fmaf(hv.w, w3.w, acc.w);
        }
        s_gp[q][d4 * 4 + 0] = acc.x;
        s_gp[q][d4 * 4 + 1] = acc.y;
        s_gp[q][d4 * 4 + 2] = acc.z;
        s_gp[q][d4 * 4 + 3] = acc.w;
    }
    __syncthreads();

    // ---- finalize g: reduce 2 partials, +b2, softsign, sigmoid. thread -> d = 2*tid, 2*tid+1.
    {
        const float2 bb = reinterpret_cast<const float2*>(b2)[tid];
        const int d = tid * 2;
        float sx = s_gp[0][d]     + s_gp[1][d]     + bb.x;
        float sy = s_gp[0][d + 1] + s_gp[1][d + 1] + bb.y;
        sx = sx / (1.0f + fabsf(sx));
        sy = sy / (1.0f + fabsf(sy));
        reinterpret_cast<float2*>(s_g)[tid] =
            make_float2(1.0f / (1.0f + __expf(-sx)), 1.0f / (1.0f + __expf(-sy)));
    }
    __syncthreads();

    // ---- Apply gate and store. Thread's col-group (tid&127) constant across its 8 rows.
    const float4 g = reinterpret_cast<const float4*>(s_g)[tid & 127];
#pragma unroll
    for (int i = 0; i < 8; ++i) {
        float4 o;
        o.x = r[i].x * g.x;
        o.y = r[i].y * g.y;
        o.z = r[i].z * g.z;
        o.w = r[i].w * g.w;
        yw[i * TPB + tid] = o;
    }
}

extern "C" void kernel_launch(void* const* d_in, const int* in_sizes, int n_in,
                              void* d_out, int out_size, void* d_ws, size_t ws_size,
                              hipStream_t stream) {
    const float* x  = (const float*)d_in[0];
    const float* W1 = (const float*)d_in[1];
    const float* b1 = (const float*)d_in[2];
    const float* W2 = (const float*)d_in[3];
    const float* b2 = (const float*)d_in[4];
    float* y = (float*)d_out;

    const int n_windows = in_sizes[0] / (WIN * D); // B * (M/WIN) = 4096
    se_block_kernel<<<dim3(n_windows), dim3(TPB), 0, stream>>>(x, W1, b1, W2, b2, y);
}